// Round 16
// baseline (116.410 us; speedup 1.0000x reference)
//
#include <hip/hip_runtime.h>
#include <math.h>
#include <stdint.h>

#define NPTS   512
#define NLIGHT 100
#define NRAY   (NPTS * NLIGHT)   // 51200
#define NS     50
#define NI     30
#define NF     80
#define HID    256
#define NEAR_  0.1f
#define FAR_   3.0f

typedef _Float16 half8  __attribute__((ext_vector_type(8)));
typedef __fp16   fp16x2 __attribute__((ext_vector_type(2)));
typedef float    f32x16 __attribute__((ext_vector_type(16)));

// ---------------- W stream layout ----------------
// 132 ksteps, one 8KB slab each: wp[gk*4096 + t*512 + lane*8 + j]
//   n = t*32 + (lane&31);  k_local = ks*16 + (lane>>5)*8 + j   (A-fragment of 32x32x16)
// layer bases: L0:0(7) L1:7 L2:24 L3:41 L4:58 (17 ea) L5:75(23) L6:98 L7:115 (17 ea)
// last kstep of each layer = bias tile; multiplied by e0 fragment.
// Windows of 2 ksteps; slab GROUPS triple-buffered in LDS (3 x 16KB). (R8-proven)
#define NKS  132
#define NW   (NKS / 2)           // 66 windows
#define WPACK_TOTAL (NKS * 4096)
#define PA_BLOCKS   (NRAY / 8)               // 6400 phase_a blocks
#define PREP_BLOCKS (WPACK_TOTAL / 256)      // 2112 prep blocks

__device__ __forceinline__ float sgpr_f(float v) {
  return __uint_as_float(__builtin_amdgcn_readfirstlane(__float_as_uint(v)));
}

// ================= sigma helper (wfr in SGPRs) =================
__device__ __forceinline__ float sigma_fast(float x, float y, float z,
                                            const float* __restrict__ wfr, float bf0) {
  float s = bf0 + wfr[0] * x + wfr[1] * y + wfr[2] * z;
  float sx = __sinf(x), cx = __cosf(x);
  float sy = __sinf(y), cy = __cosf(y);
  float sz = __sinf(z), cz = __cosf(z);
#pragma unroll
  for (int k = 0; k < 4; ++k) {
    s += wfr[3 + 6 * k + 0] * sx + wfr[3 + 6 * k + 1] * sy + wfr[3 + 6 * k + 2] * sz;
    s += wfr[3 + 6 * k + 3] * cx + wfr[3 + 6 * k + 4] * cy + wfr[3 + 6 * k + 5] * cz;
    if (k < 3) {
      const float sx2 = 2.0f * sx * cx, cx2 = 1.0f - 2.0f * sx * sx;
      const float sy2 = 2.0f * sy * cy, cy2 = 1.0f - 2.0f * sy * sy;
      const float sz2 = 2.0f * sz * cz, cz2 = 1.0f - 2.0f * sz * sz;
      sx = sx2; cx = cx2; sy = sy2; cy = cy2; sz = sz2; cz = cz2;
    }
  }
  return s;
}

// ================= merged front kernel: phase_a blocks + prep_w blocks =================
struct RayScratch2 {
  float cdf[NS - 1];   // 49 normalized cdf values
  float zs[NI];        // 30 importance samples
  float zall[NF];      // 80 merged z values
  float af[96];        // 96 fine alphas (zero-padded) for coalesced pack
};

__global__ __launch_bounds__(256, 8) void front(
    const float* __restrict__ pts, const float* __restrict__ lights,
    const float* __restrict__ sincol, const float* __restrict__ normal,
    const float* __restrict__ rb, const float* __restrict__ wf,
    const float* __restrict__ bf,
    const float* __restrict__ w0, const float* __restrict__ b0,
    const float* __restrict__ w1, const float* __restrict__ b1,
    const float* __restrict__ w2, const float* __restrict__ b2,
    const float* __restrict__ w3, const float* __restrict__ b3,
    const float* __restrict__ w4, const float* __restrict__ b4,
    const float* __restrict__ w5, const float* __restrict__ b5,
    const float* __restrict__ w6, const float* __restrict__ b6,
    const float* __restrict__ w7, const float* __restrict__ b7,
    _Float16* __restrict__ wp,
    _Float16* __restrict__ apack, float* __restrict__ cosin_out) {
  __shared__ RayScratch2 sh[8];

  if (blockIdx.x >= PA_BLOCKS) {
    // ---------------- prep_w part ----------------
    const int t = (blockIdx.x - PA_BLOCKS) * 256 + threadIdx.x;
    const int j    = t & 7;
    const int lane = (t >> 3) & 63;
    const int tile = (t >> 9) & 7;
    const int gk   = t >> 12;
    const int n    = tile * 32 + (lane & 31);
    const int kin  = (lane >> 5) * 8 + j;

    int base, KST, l; const float *W, *B;
    if      (gk < 7)   { l=0; base=0;   KST=7;  W=w0; B=b0; }
    else if (gk < 24)  { l=1; base=7;   KST=17; W=w1; B=b1; }
    else if (gk < 41)  { l=2; base=24;  KST=17; W=w2; B=b2; }
    else if (gk < 58)  { l=3; base=41;  KST=17; W=w3; B=b3; }
    else if (gk < 75)  { l=4; base=58;  KST=17; W=w4; B=b4; }
    else if (gk < 98)  { l=5; base=75;  KST=23; W=w5; B=b5; }
    else if (gk < 115) { l=6; base=98;  KST=17; W=w6; B=b6; }
    else               { l=7; base=115; KST=17; W=w7; B=b7; }
    const int ks = gk - base;
    const int k  = ks * 16 + kin;
    float v = 0.0f;
    if (ks == KST - 1)   { if (kin == 0) v = B[n]; }
    else if (l == 0)     { if (k < 80) v = W[k * HID + n]; }
    else if (l == 5)     { if (k < 80) v = W[k * HID + n];
                           else if (k >= 96) v = W[(k - 16) * HID + n]; }
    else                 { v = W[k * HID + n]; }
    wp[t] = (_Float16)v;
    return;
  }

  // ---------------- phase_a part: 2 rays per wave (half-wave = one ray) ----------------
  const int wave = threadIdx.x >> 6;
  const int lane = threadIdx.x & 63;
  const int half = lane >> 5, l32 = lane & 31;
  const int ray  = (blockIdx.x * 4 + wave) * 2 + half;
  const int i = ray / NLIGHT, j = ray - i * NLIGHT;
  RayScratch2& S = sh[wave * 2 + half];

  float wfr[27];
#pragma unroll
  for (int k = 0; k < 27; ++k) wfr[k] = sgpr_f(wf[k]);
  const float bf0 = sgpr_f(bf[0]);
  const float DZ = (FAR_ - NEAR_) / (float)(NS - 1);

  const float px = pts[3 * i + 0], py = pts[3 * i + 1], pz = pts[3 * i + 2];
  const float dx = lights[3 * j + 0] - px;
  const float dy = lights[3 * j + 1] - py;
  const float dz = lights[3 * j + 2] - pz;
  const float nrm = sqrtf(dx * dx + dy * dy + dz * dz);
  const float rdx = dx / nrm, rdy = dy / nrm, rdz = dz / nrm;
  const float n2 = sqrtf(rdx * rdx + rdy * rdy + rdz * rdz);

  if (l32 == 0) {
    const float dotn = rdx * normal[3 * i + 0] + rdy * normal[3 * i + 1] + rdz * normal[3 * i + 2];
    cosin_out[ray] = (dotn > 0.0f) ? 1.0f : 0.0f;
  }

  const int k1 = l32, k2 = l32 + 32;
  const float sc = sincol[j];
  float a1, a2 = 0.0f;
  {
    const float z1 = NEAR_ + k1 * DZ;
    const float rb1 = rb[(size_t)ray * NS + k1];
    const float b1v = sc * z1 * 0.01f * (rb1 * 2.0f - 1.0f);
    const float s1v = sigma_fast(px + rdx * z1 + b1v, py + rdy * z1 + b1v, pz + rdz * z1 + b1v, wfr, bf0);
    a1 = 1.0f - __expf(-fmaxf(s1v, 0.0f) * DZ);
  }
  if (k2 < NS) {
    const float z2 = NEAR_ + k2 * DZ;
    const float rb2 = rb[(size_t)ray * NS + k2];
    const float b2v = sc * z2 * 0.01f * (rb2 * 2.0f - 1.0f);
    const float s2v = sigma_fast(px + rdx * z2 + b2v, py + rdy * z2 + b2v, pz + rdz * z2 + b2v, wfr, bf0);
    const float d2 = (k2 < NS - 1) ? DZ : 1e10f;
    a2 = 1.0f - __expf(-fmaxf(s2v, 0.0f) * d2);
  }

  // transmittance: exclusive product scan over 50 (two width-32 chunks)
  float v1 = 1.0f - a1 + 1e-10f;
  float v2 = (k2 < NS) ? (1.0f - a2 + 1e-10f) : 1.0f;
  float s1 = v1, s2 = v2;
#pragma unroll
  for (int off = 1; off < 32; off <<= 1) {
    const float o1 = __shfl_up(s1, off, 32);
    const float o2 = __shfl_up(s2, off, 32);
    if (l32 >= off) { s1 *= o1; s2 *= o2; }
  }
  const float tot1 = __shfl(s1, 31, 32);
  float e1 = __shfl_up(s1, 1, 32); if (l32 == 0) e1 = 1.0f;
  float e2 = __shfl_up(s2, 1, 32); e2 = (l32 == 0) ? tot1 : tot1 * e2;

  const float w1v = a1 * e1, w2v = a2 * e2;
  float ww1 = (k1 >= 1) ? (w1v + 1e-5f) : 0.0f;
  float ww2 = (k2 <= NS - 2 && k2 < NS) ? (w2v + 1e-5f) : 0.0f;

  float t = ww1 + ww2;
#pragma unroll
  for (int off = 1; off < 32; off <<= 1) t += __shfl_xor(t, off, 32);
  const float rn = 1.0f / t;

  float c1 = ww1, c2 = ww2;
#pragma unroll
  for (int off = 1; off < 32; off <<= 1) {
    const float o1 = __shfl_up(c1, off, 32);
    const float o2 = __shfl_up(c2, off, 32);
    if (l32 >= off) { c1 += o1; c2 += o2; }
  }
  const float tots1 = __shfl(c1, 31, 32);
  c2 += tots1;
  S.cdf[k1] = c1 * rn;
  if (k2 <= NS - 2) S.cdf[k2] = c2 * rn;

  // importance sampling
  float zsv = 0.0f;
  if (l32 < NI) {
    const float u = (float)l32 / (float)(NI - 1);
    int ind = 0;
#pragma unroll
    for (int k = 0; k < NS - 1; ++k)
      if (S.cdf[k] <= u) ind = k + 1;
    const int below = max(ind - 1, 0);
    const int above = min(ind, NS - 2);
    const float c0 = S.cdf[below], c1v = S.cdf[above];
    const float b0v = NEAR_ + ((float)below + 0.5f) * DZ;
    const float b1v = NEAR_ + ((float)above + 0.5f) * DZ;
    float den = c1v - c0;
    if (den < 1e-5f) den = 1.0f;
    zsv = b0v + (u - c0) / den * (b1v - b0v);
    S.zs[l32] = zsv;
  }

  // rank merge (zv affine both sides; consistent fp compares)
  {
    const float z1 = NEAR_ + k1 * DZ;
    const float z2 = NEAR_ + k2 * DZ;
    int cnt1 = 0, cnt2 = 0;
#pragma unroll
    for (int m = 0; m < NI; ++m) {
      const float zm = S.zs[m];
      cnt1 += (zm < z1) ? 1 : 0;
      cnt2 += (zm < z2) ? 1 : 0;
    }
    S.zall[k1 + cnt1] = z1;
    if (k2 < NS) S.zall[k2 + cnt2] = z2;
  }
  if (l32 < NI) {
    int cnt = 0;
#pragma unroll
    for (int k = 0; k < NS; ++k)
      cnt += ((NEAR_ + k * DZ) <= zsv) ? 1 : 0;
    S.zall[l32 + cnt] = zsv;
  }

  // fine sigma into LDS af[96] (3 rounds of 32; zero pad for k >= NF)
#pragma unroll
  for (int r = 0; r < 3; ++r) {
    const int k = l32 + 32 * r;
    float alpha = 0.0f;
    if (k < NF) {
      const float z = S.zall[k];
      const float d = ((k < NF - 1) ? (S.zall[k + 1] - z) : 1e10f) * n2;
      const float sig = sigma_fast(px + rdx * z, py + rdy * z, pz + rdz * z, wfr, bf0);
      alpha = 1.0f - __expf(-fmaxf(sig, 0.0f) * d);
    }
    S.af[k] = alpha;
  }

  // coalesced pack: lanes 0..11 of each half-wave emit one half8 (16B) chunk each
  {
    const int rt = ray >> 5, rr = ray & 31;
    if (l32 < 12) {
      const int ks = l32 >> 1, hh = l32 & 1;
      half8 v;
#pragma unroll
      for (int jj = 0; jj < 8; ++jj) v[jj] = (_Float16)S.af[ks * 16 + hh * 8 + jj];
      *(half8*)(apack + ((size_t)(rt * 6 + ks) * 64 + rr + 32 * hh) * 8) = v;
    }
  }
}

// ======= Phase B (R8/R10-proven): windowed 2-kstep triple-buffered W-stream MLP =======
template <int V> struct IC { static constexpr int val = V; };
template <int I, int N, typename F>
__device__ __forceinline__ void static_for(F&& f) {
  if constexpr (I < N) { f(IC<I>{}); static_for<I + 1, N>((F&&)f); }
}

__device__ __forceinline__ void gload16(const _Float16* g, _Float16* l) {
  __builtin_amdgcn_global_load_lds(
      (const __attribute__((address_space(1))) uint32_t*)g,
      (__attribute__((address_space(3))) uint32_t*)l, 16, 0, 0);
}

// slab gk -> LDS f16 offset: group buffer ((gk>>1)%3)*8192 + (gk&1)*4096
__device__ __forceinline__ void prefetch_slab(const _Float16* __restrict__ wp,
                                              _Float16* SLAB, int gk, int off,
                                              int wave, int lane) {
  const _Float16* g = wp + ((size_t)gk << 12) + (wave << 9);
  _Float16* lb = SLAB + off + (wave << 9);
  gload16(g + lane * 8, lb);
  gload16(g + 2048 + lane * 8, lb + 2048);
}

// Window preamble (even GK): lgkm(0) -> counted vmcnt -> ONE barrier -> prefetch
// group GK/2+2 (2 slabs). Both ksteps of the window read staged slabs and MFMA.
template <int GK, bool FROM_ALPHA>
__device__ __forceinline__ void kstep(f32x16 (&acc)[8], const half8& breg,
                                      const _Float16* __restrict__ wp,
                                      _Float16* SLAB, const _Float16* ALPHA,
                                      int aks, int wave, int lane) {
  constexpr int w = GK >> 1;
  if constexpr ((GK & 1) == 0) {
    asm volatile("s_waitcnt lgkmcnt(0)" ::: "memory");
    constexpr int wait = (w < NW - 1) ? 4 : 0;
    asm volatile("s_waitcnt vmcnt(%0)" :: "i"(wait) : "memory");
    __builtin_amdgcn_s_barrier();
    constexpr int pg = w + 2;
    if constexpr (pg < NW) {
      constexpr int o0 = ((pg % 3) * 8192);
      prefetch_slab(wp, SLAB, 2 * pg,     o0,        wave, lane);
      prefetch_slab(wp, SLAB, 2 * pg + 1, o0 + 4096, wave, lane);
    }
  }
  half8 bfr;
  if constexpr (FROM_ALPHA)
    bfr = *(const half8*)(ALPHA + ((wave * 6 + aks) * 64 + lane) * 8);
  else
    bfr = breg;
  constexpr int off = (w % 3) * 8192 + (GK & 1) * 4096;
  half8 wfv[8];
#pragma unroll
  for (int t = 0; t < 8; ++t)
    wfv[t] = *(const half8*)(SLAB + off + t * 512 + lane * 8);
  __builtin_amdgcn_s_setprio(1);
#pragma unroll
  for (int t = 0; t < 8; ++t)
    acc[t] = __builtin_amdgcn_mfma_f32_32x32x16_f16(wfv[t], bfr, acc[t], 0, 0, 0);
  __builtin_amdgcn_s_setprio(0);
}

__device__ __forceinline__ uint32_t pk2(float a, float b) {
  union { fp16x2 h; uint32_t u; } c;
  c.h = __builtin_amdgcn_cvt_pkrtz(a, b);
  return c.u;
}
__device__ __forceinline__ uint32_t shx32(uint32_t v) {
  return (uint32_t)__shfl_xor((int)v, 32, 64);
}
__device__ __forceinline__ half8 mk8(uint32_t a, uint32_t b, uint32_t c, uint32_t d) {
  union { uint32_t w[4]; half8 h; } u; u.w[0]=a; u.w[1]=b; u.w[2]=c; u.w[3]=d; return u.h;
}

// C fragment (row=(q&3)+8*(q>>2)+4*hi, col=ray) -> next-layer B fragments, in-register
__device__ __forceinline__ void epilogue(f32x16 (&acc)[8], half8 (&actB)[16], int hi) {
  const f32x16 ZV = {};
#pragma unroll
  for (int t = 0; t < 8; ++t) {
    float r[16];
#pragma unroll
    for (int q = 0; q < 16; ++q) r[q] = fmaxf(acc[t][q], 0.0f);
    const uint32_t A01 = pk2(r[0], r[1]),   A23 = pk2(r[2], r[3]);
    const uint32_t A45 = pk2(r[4], r[5]),   A67 = pk2(r[6], r[7]);
    const uint32_t A89 = pk2(r[8], r[9]),   Aab = pk2(r[10], r[11]);
    const uint32_t Acd = pk2(r[12], r[13]), Aef = pk2(r[14], r[15]);
    const uint32_t S01 = shx32(A01), S23 = shx32(A23), S45 = shx32(A45), S67 = shx32(A67);
    const uint32_t S89 = shx32(A89), Sab = shx32(Aab), Scd = shx32(Acd), Sef = shx32(Aef);
    actB[2 * t]     = mk8(hi ? S45 : A01, hi ? S67 : A23, hi ? A45 : S01, hi ? A67 : S23);
    actB[2 * t + 1] = mk8(hi ? Scd : A89, hi ? Sef : Aab, hi ? Acd : S89, hi ? Aef : Sab);
    acc[t] = ZV;
  }
}

__global__ __launch_bounds__(256, 2) void mlp_fw(
    const _Float16* __restrict__ apack, const float* __restrict__ cosin_buf,
    const _Float16* __restrict__ wp, const float* __restrict__ wl,
    const float* __restrict__ bl, float* __restrict__ out) {
  __shared__ _Float16 SLAB[3 * 8192];      // 48 KB: 3 group buffers x 2 slabs
  __shared__ _Float16 ALPHA[12288];        // 24 KB: 4 tiles x 6 ks x 64 x 8
  const int tid = threadIdx.x, wave = tid >> 6, lane = tid & 63;
  const int hi = lane >> 5, ray = lane & 31;
  const int rtile = blockIdx.x * 4 + wave;

  half8 bfrag = {};
  if (hi == 0) bfrag[0] = (_Float16)1.0f;

  // ---- prologue: stage ALPHA (6 gloads/thread), then groups 0 and 1 (8 gloads) ----
  const _Float16* abase = apack + (size_t)blockIdx.x * 12288;
#pragma unroll
  for (int s = 0; s < 6; ++s)
    gload16(abase + s * 2048 + wave * 512 + lane * 8, ALPHA + s * 2048 + wave * 512);
  prefetch_slab(wp, SLAB, 0, 0,           wave, lane);
  prefetch_slab(wp, SLAB, 1, 4096,        wave, lane);
  prefetch_slab(wp, SLAB, 2, 8192,        wave, lane);
  prefetch_slab(wp, SLAB, 3, 8192 + 4096, wave, lane);
  // window 0 preamble's vmcnt(4) drains ALPHA + group 0, leaves group 1 in flight.

  f32x16 acc[8]; const f32x16 ZV = {};
#pragma unroll
  for (int t = 0; t < 8; ++t) acc[t] = ZV;
  half8 actB[16];

#define KSA(GK, AKS) kstep<GK, true >(acc, bfrag, wp, SLAB, ALPHA, AKS, wave, lane)
#define KSR(GK, BFR) kstep<GK, false>(acc, (BFR), wp, SLAB, ALPHA, 0,   wave, lane)

  // L0: alpha(6) + bias
  static_for<0, 7>([&](auto ic) { constexpr int ks = decltype(ic)::val;
    if constexpr (ks < 6) KSA(0 + ks, ks); else KSR(0 + ks, bfrag); });
  epilogue(acc, actB, hi);
  // L1..L4
  static_for<0, 17>([&](auto ic) { constexpr int ks = decltype(ic)::val;
    if constexpr (ks < 16) KSR(7 + ks, actB[ks]); else KSR(7 + ks, bfrag); });
  epilogue(acc, actB, hi);
  static_for<0, 17>([&](auto ic) { constexpr int ks = decltype(ic)::val;
    if constexpr (ks < 16) KSR(24 + ks, actB[ks]); else KSR(24 + ks, bfrag); });
  epilogue(acc, actB, hi);
  static_for<0, 17>([&](auto ic) { constexpr int ks = decltype(ic)::val;
    if constexpr (ks < 16) KSR(41 + ks, actB[ks]); else KSR(41 + ks, bfrag); });
  epilogue(acc, actB, hi);
  static_for<0, 17>([&](auto ic) { constexpr int ks = decltype(ic)::val;
    if constexpr (ks < 16) KSR(58 + ks, actB[ks]); else KSR(58 + ks, bfrag); });
  epilogue(acc, actB, hi);
  // L5: alpha(6) + h(16) + bias
  static_for<0, 23>([&](auto ic) { constexpr int ks = decltype(ic)::val;
    if constexpr (ks < 6)       KSA(75 + ks, ks);
    else if constexpr (ks < 22) KSR(75 + ks, actB[ks - 6]);
    else                        KSR(75 + ks, bfrag); });
  epilogue(acc, actB, hi);
  // L6, L7
  static_for<0, 17>([&](auto ic) { constexpr int ks = decltype(ic)::val;
    if constexpr (ks < 16) KSR(98 + ks, actB[ks]); else KSR(98 + ks, bfrag); });
  epilogue(acc, actB, hi);
  static_for<0, 17>([&](auto ic) { constexpr int ks = decltype(ic)::val;
    if constexpr (ks < 16) KSR(115 + ks, actB[ks]); else KSR(115 + ks, bfrag); });
  epilogue(acc, actB, hi);
#undef KSA
#undef KSR

  // final: dot(h, w_last) -> sigmoid -> * cosin
  float p = 0.0f;
#pragma unroll
  for (int s = 0; s < 16; ++s) {
    const float* wq = wl + s * 16 + hi * 8;
#pragma unroll
    for (int j = 0; j < 8; ++j) p += (float)actB[s][j] * wq[j];
  }
  p += __shfl_xor(p, 32, 64);
  if (hi == 0) {
    const int rg = rtile * 32 + ray;
    out[rg] = (1.0f / (1.0f + __expf(-(p + bl[0])))) * cosin_buf[rg];
  }
}

// ================= launch =================
extern "C" void kernel_launch(void* const* d_in, const int* in_sizes, int n_in,
                              void* d_out, int out_size, void* d_ws, size_t ws_size,
                              hipStream_t stream) {
  const float* pts    = (const float*)d_in[0];
  const float* lights = (const float*)d_in[1];
  const float* sincol = (const float*)d_in[2];
  const float* normal = (const float*)d_in[3];
  const float* rb     = (const float*)d_in[4];
  const float* wf     = (const float*)d_in[5];
  const float* bf     = (const float*)d_in[6];
  const float* wlast  = (const float*)d_in[7];
  const float* blast  = (const float*)d_in[8];
  const float* w0 = (const float*)d_in[9];  const float* b0 = (const float*)d_in[10];
  const float* w1 = (const float*)d_in[11]; const float* b1 = (const float*)d_in[12];
  const float* w2 = (const float*)d_in[13]; const float* b2 = (const float*)d_in[14];
  const float* w3 = (const float*)d_in[15]; const float* b3 = (const float*)d_in[16];
  const float* w4 = (const float*)d_in[17]; const float* b4 = (const float*)d_in[18];
  const float* w5 = (const float*)d_in[19]; const float* b5 = (const float*)d_in[20];
  const float* w6 = (const float*)d_in[21]; const float* b6 = (const float*)d_in[22];
  const float* w7 = (const float*)d_in[23]; const float* b7 = (const float*)d_in[24];

  char* ws = (char*)d_ws;
  _Float16* apack  = (_Float16*)ws;                                  // NRAY*96 f16
  float* cosin_buf = (float*)(ws + (size_t)NRAY * 96 * 2);           // NRAY f32
  _Float16* wpack  = (_Float16*)(ws + (size_t)NRAY * 96 * 2 + (size_t)NRAY * 4);
  float* out = (float*)d_out;

  front<<<PA_BLOCKS + PREP_BLOCKS, 256, 0, stream>>>(
      pts, lights, sincol, normal, rb, wf, bf,
      w0, b0, w1, b1, w2, b2, w3, b3, w4, b4, w5, b5, w6, b6, w7, b7,
      wpack, apack, cosin_buf);
  mlp_fw<<<NRAY / 128, 256, 0, stream>>>(apack, cosin_buf, wpack, wlast, blast, out);
}

// Round 17
// 109.237 us; speedup vs baseline: 1.0657x; 1.0657x over previous
//
#include <hip/hip_runtime.h>
#include <math.h>
#include <stdint.h>

#define NPTS   512
#define NLIGHT 100
#define NRAY   (NPTS * NLIGHT)   // 51200
#define NS     50
#define NI     30
#define NF     80
#define HID    256
#define NEAR_  0.1f
#define FAR_   3.0f

typedef _Float16 half8  __attribute__((ext_vector_type(8)));
typedef __fp16   fp16x2 __attribute__((ext_vector_type(2)));
typedef float    f32x16 __attribute__((ext_vector_type(16)));

// ---------------- W stream layout ----------------
// 132 ksteps, one 8KB slab each: wp[gk*4096 + t*512 + lane*8 + j]
//   n = t*32 + (lane&31);  k_local = ks*16 + (lane>>5)*8 + j   (A-fragment of 32x32x16)
// layer bases: L0:0(7) L1:7 L2:24 L3:41 L4:58 (17 ea) L5:75(23) L6:98 L7:115 (17 ea)
// last kstep of each layer = bias tile; multiplied by e0 fragment.
// Windows of 2 ksteps; slab GROUPS triple-buffered in LDS (3 x 16KB). (R8-proven)
#define NKS  132
#define NW   (NKS / 2)           // 66 windows
#define WPACK_TOTAL (NKS * 4096)
#define PREP_BLOCKS (WPACK_TOTAL / 256)      // 2112 prep blocks (dispatched FIRST)
#define PA_BLOCKS   (NRAY / 8)               // 6400 phase_a blocks

__device__ __forceinline__ float sgpr_f(float v) {
  return __uint_as_float(__builtin_amdgcn_readfirstlane(__float_as_uint(v)));
}

// ================= sigma helper (wfr in SGPRs) =================
__device__ __forceinline__ float sigma_fast(float x, float y, float z,
                                            const float* __restrict__ wfr, float bf0) {
  float s = bf0 + wfr[0] * x + wfr[1] * y + wfr[2] * z;
  float sx = __sinf(x), cx = __cosf(x);
  float sy = __sinf(y), cy = __cosf(y);
  float sz = __sinf(z), cz = __cosf(z);
#pragma unroll
  for (int k = 0; k < 4; ++k) {
    s += wfr[3 + 6 * k + 0] * sx + wfr[3 + 6 * k + 1] * sy + wfr[3 + 6 * k + 2] * sz;
    s += wfr[3 + 6 * k + 3] * cx + wfr[3 + 6 * k + 4] * cy + wfr[3 + 6 * k + 5] * cz;
    if (k < 3) {
      const float sx2 = 2.0f * sx * cx, cx2 = 1.0f - 2.0f * sx * sx;
      const float sy2 = 2.0f * sy * cy, cy2 = 1.0f - 2.0f * sy * sy;
      const float sz2 = 2.0f * sz * cz, cz2 = 1.0f - 2.0f * sz * sz;
      sx = sx2; cx = cx2; sy = sy2; cy = cy2; sz = sz2; cz = cz2;
    }
  }
  return s;
}

// ================= merged front kernel: prep_w blocks FIRST, then phase_a =================
struct RayScratch2 {
  float cdf[NS - 1];   // 49 normalized cdf values (nondecreasing)
  float zs[NI];        // 30 importance samples (nondecreasing)
  float zall[NF];      // 80 merged z values
  float af[96];        // 96 fine alphas (zero-padded) for coalesced pack
};

__global__ __launch_bounds__(256, 8) void front(
    const float* __restrict__ pts, const float* __restrict__ lights,
    const float* __restrict__ sincol, const float* __restrict__ normal,
    const float* __restrict__ rb, const float* __restrict__ wf,
    const float* __restrict__ bf,
    const float* __restrict__ w0, const float* __restrict__ b0,
    const float* __restrict__ w1, const float* __restrict__ b1,
    const float* __restrict__ w2, const float* __restrict__ b2,
    const float* __restrict__ w3, const float* __restrict__ b3,
    const float* __restrict__ w4, const float* __restrict__ b4,
    const float* __restrict__ w5, const float* __restrict__ b5,
    const float* __restrict__ w6, const float* __restrict__ b6,
    const float* __restrict__ w7, const float* __restrict__ b7,
    _Float16* __restrict__ wp,
    _Float16* __restrict__ apack, float* __restrict__ cosin_out) {
  __shared__ RayScratch2 sh[8];

  if (blockIdx.x < PREP_BLOCKS) {
    // ---------------- prep_w part (first: gathers drain under phase_a's shadow) --------
    const int t = blockIdx.x * 256 + threadIdx.x;
    const int j    = t & 7;
    const int lane = (t >> 3) & 63;
    const int tile = (t >> 9) & 7;
    const int gk   = t >> 12;
    const int n    = tile * 32 + (lane & 31);
    const int kin  = (lane >> 5) * 8 + j;

    int base, KST, l; const float *W, *B;
    if      (gk < 7)   { l=0; base=0;   KST=7;  W=w0; B=b0; }
    else if (gk < 24)  { l=1; base=7;   KST=17; W=w1; B=b1; }
    else if (gk < 41)  { l=2; base=24;  KST=17; W=w2; B=b2; }
    else if (gk < 58)  { l=3; base=41;  KST=17; W=w3; B=b3; }
    else if (gk < 75)  { l=4; base=58;  KST=17; W=w4; B=b4; }
    else if (gk < 98)  { l=5; base=75;  KST=23; W=w5; B=b5; }
    else if (gk < 115) { l=6; base=98;  KST=17; W=w6; B=b6; }
    else               { l=7; base=115; KST=17; W=w7; B=b7; }
    const int ks = gk - base;
    const int k  = ks * 16 + kin;
    float v = 0.0f;
    if (ks == KST - 1)   { if (kin == 0) v = B[n]; }
    else if (l == 0)     { if (k < 80) v = W[k * HID + n]; }
    else if (l == 5)     { if (k < 80) v = W[k * HID + n];
                           else if (k >= 96) v = W[(k - 16) * HID + n]; }
    else                 { v = W[k * HID + n]; }
    wp[t] = (_Float16)v;
    return;
  }

  // ---------------- phase_a part: 2 rays per wave (half-wave = one ray) ----------------
  const int pablk = blockIdx.x - PREP_BLOCKS;
  const int wave = threadIdx.x >> 6;
  const int lane = threadIdx.x & 63;
  const int half = lane >> 5, l32 = lane & 31;
  const int ray  = (pablk * 4 + wave) * 2 + half;
  const int i = ray / NLIGHT, j = ray - i * NLIGHT;
  RayScratch2& S = sh[wave * 2 + half];

  float wfr[27];
#pragma unroll
  for (int k = 0; k < 27; ++k) wfr[k] = sgpr_f(wf[k]);
  const float bf0 = sgpr_f(bf[0]);
  const float DZ = (FAR_ - NEAR_) / (float)(NS - 1);

  const float px = pts[3 * i + 0], py = pts[3 * i + 1], pz = pts[3 * i + 2];
  const float dx = lights[3 * j + 0] - px;
  const float dy = lights[3 * j + 1] - py;
  const float dz = lights[3 * j + 2] - pz;
  const float nrm = sqrtf(dx * dx + dy * dy + dz * dz);
  const float rdx = dx / nrm, rdy = dy / nrm, rdz = dz / nrm;
  const float n2 = sqrtf(rdx * rdx + rdy * rdy + rdz * rdz);

  if (l32 == 0) {
    const float dotn = rdx * normal[3 * i + 0] + rdy * normal[3 * i + 1] + rdz * normal[3 * i + 2];
    cosin_out[ray] = (dotn > 0.0f) ? 1.0f : 0.0f;
  }

  const int k1 = l32, k2 = l32 + 32;
  const float sc = sincol[j];
  float a1, a2 = 0.0f;
  {
    const float z1 = NEAR_ + k1 * DZ;
    const float rb1 = rb[(size_t)ray * NS + k1];
    const float b1v = sc * z1 * 0.01f * (rb1 * 2.0f - 1.0f);
    const float s1v = sigma_fast(px + rdx * z1 + b1v, py + rdy * z1 + b1v, pz + rdz * z1 + b1v, wfr, bf0);
    a1 = 1.0f - __expf(-fmaxf(s1v, 0.0f) * DZ);
  }
  if (k2 < NS) {
    const float z2 = NEAR_ + k2 * DZ;
    const float rb2 = rb[(size_t)ray * NS + k2];
    const float b2v = sc * z2 * 0.01f * (rb2 * 2.0f - 1.0f);
    const float s2v = sigma_fast(px + rdx * z2 + b2v, py + rdy * z2 + b2v, pz + rdz * z2 + b2v, wfr, bf0);
    const float d2 = (k2 < NS - 1) ? DZ : 1e10f;
    a2 = 1.0f - __expf(-fmaxf(s2v, 0.0f) * d2);
  }

  // transmittance: exclusive product scan over 50 (two width-32 chunks)
  float v1 = 1.0f - a1 + 1e-10f;
  float v2 = (k2 < NS) ? (1.0f - a2 + 1e-10f) : 1.0f;
  float s1 = v1, s2 = v2;
#pragma unroll
  for (int off = 1; off < 32; off <<= 1) {
    const float o1 = __shfl_up(s1, off, 32);
    const float o2 = __shfl_up(s2, off, 32);
    if (l32 >= off) { s1 *= o1; s2 *= o2; }
  }
  const float tot1 = __shfl(s1, 31, 32);
  float e1 = __shfl_up(s1, 1, 32); if (l32 == 0) e1 = 1.0f;
  float e2 = __shfl_up(s2, 1, 32); e2 = (l32 == 0) ? tot1 : tot1 * e2;

  const float w1v = a1 * e1, w2v = a2 * e2;
  float ww1 = (k1 >= 1) ? (w1v + 1e-5f) : 0.0f;
  float ww2 = (k2 <= NS - 2 && k2 < NS) ? (w2v + 1e-5f) : 0.0f;

  float t = ww1 + ww2;
#pragma unroll
  for (int off = 1; off < 32; off <<= 1) t += __shfl_xor(t, off, 32);
  const float rn = 1.0f / t;

  float c1 = ww1, c2 = ww2;
#pragma unroll
  for (int off = 1; off < 32; off <<= 1) {
    const float o1 = __shfl_up(c1, off, 32);
    const float o2 = __shfl_up(c2, off, 32);
    if (l32 >= off) { c1 += o1; c2 += o2; }
  }
  const float tots1 = __shfl(c1, 31, 32);
  c2 += tots1;
  S.cdf[k1] = c1 * rn;
  if (k2 <= NS - 2) S.cdf[k2] = c2 * rn;

  // importance sampling: side='right' searchsorted via 6-step binary count
  // (cdf nondecreasing -> predicate (cdf[k] <= u) is a true-prefix; binary == linear)
  float zsv = 0.0f;
  if (l32 < NI) {
    const float u = (float)l32 / (float)(NI - 1);
    int ind = 0;
#pragma unroll
    for (int step = 32; step >= 1; step >>= 1) {
      const int nxt = ind + step;
      if (nxt <= NS - 1 && S.cdf[nxt - 1] <= u) ind = nxt;
    }
    const int below = max(ind - 1, 0);
    const int above = min(ind, NS - 2);
    const float c0 = S.cdf[below], c1v = S.cdf[above];
    const float b0v = NEAR_ + ((float)below + 0.5f) * DZ;
    const float b1v = NEAR_ + ((float)above + 0.5f) * DZ;
    float den = c1v - c0;
    if (den < 1e-5f) den = 1.0f;
    zsv = b0v + (u - c0) / den * (b1v - b0v);
    S.zs[l32] = zsv;
  }

  // rank merge: count of zs[m] < z via 5-step binary lower-bound (zs nondecreasing)
  {
    const float z1 = NEAR_ + k1 * DZ;
    const float z2 = NEAR_ + k2 * DZ;
    int cnt1 = 0, cnt2 = 0;
#pragma unroll
    for (int step = 16; step >= 1; step >>= 1) {
      { const int nxt = cnt1 + step; if (nxt <= NI && S.zs[nxt - 1] < z1) cnt1 = nxt; }
      { const int nxt = cnt2 + step; if (nxt <= NI && S.zs[nxt - 1] < z2) cnt2 = nxt; }
    }
    S.zall[k1 + cnt1] = z1;
    if (k2 < NS) S.zall[k2 + cnt2] = z2;
  }
  if (l32 < NI) {
    int cnt = 0;
#pragma unroll
    for (int k = 0; k < NS; ++k)
      cnt += ((NEAR_ + k * DZ) <= zsv) ? 1 : 0;
    S.zall[l32 + cnt] = zsv;
  }

  // fine sigma into LDS af[96] (3 rounds of 32; zero pad for k >= NF)
#pragma unroll
  for (int r = 0; r < 3; ++r) {
    const int k = l32 + 32 * r;
    float alpha = 0.0f;
    if (k < NF) {
      const float z = S.zall[k];
      const float d = ((k < NF - 1) ? (S.zall[k + 1] - z) : 1e10f) * n2;
      const float sig = sigma_fast(px + rdx * z, py + rdy * z, pz + rdz * z, wfr, bf0);
      alpha = 1.0f - __expf(-fmaxf(sig, 0.0f) * d);
    }
    S.af[k] = alpha;
  }

  // coalesced pack: lanes 0..11 of each half-wave emit one half8 (16B) chunk each
  {
    const int rt = ray >> 5, rr = ray & 31;
    if (l32 < 12) {
      const int ks = l32 >> 1, hh = l32 & 1;
      half8 v;
#pragma unroll
      for (int jj = 0; jj < 8; ++jj) v[jj] = (_Float16)S.af[ks * 16 + hh * 8 + jj];
      *(half8*)(apack + ((size_t)(rt * 6 + ks) * 64 + rr + 32 * hh) * 8) = v;
    }
  }
}

// ======= Phase B (R8/R10-proven): windowed 2-kstep triple-buffered W-stream MLP =======
template <int V> struct IC { static constexpr int val = V; };
template <int I, int N, typename F>
__device__ __forceinline__ void static_for(F&& f) {
  if constexpr (I < N) { f(IC<I>{}); static_for<I + 1, N>((F&&)f); }
}

__device__ __forceinline__ void gload16(const _Float16* g, _Float16* l) {
  __builtin_amdgcn_global_load_lds(
      (const __attribute__((address_space(1))) uint32_t*)g,
      (__attribute__((address_space(3))) uint32_t*)l, 16, 0, 0);
}

// slab gk -> LDS f16 offset: group buffer ((gk>>1)%3)*8192 + (gk&1)*4096
__device__ __forceinline__ void prefetch_slab(const _Float16* __restrict__ wp,
                                              _Float16* SLAB, int gk, int off,
                                              int wave, int lane) {
  const _Float16* g = wp + ((size_t)gk << 12) + (wave << 9);
  _Float16* lb = SLAB + off + (wave << 9);
  gload16(g + lane * 8, lb);
  gload16(g + 2048 + lane * 8, lb + 2048);
}

// Window preamble (even GK): lgkm(0) -> counted vmcnt -> ONE barrier -> prefetch
// group GK/2+2 (2 slabs). Both ksteps of the window read staged slabs and MFMA.
template <int GK, bool FROM_ALPHA>
__device__ __forceinline__ void kstep(f32x16 (&acc)[8], const half8& breg,
                                      const _Float16* __restrict__ wp,
                                      _Float16* SLAB, const _Float16* ALPHA,
                                      int aks, int wave, int lane) {
  constexpr int w = GK >> 1;
  if constexpr ((GK & 1) == 0) {
    asm volatile("s_waitcnt lgkmcnt(0)" ::: "memory");
    constexpr int wait = (w < NW - 1) ? 4 : 0;
    asm volatile("s_waitcnt vmcnt(%0)" :: "i"(wait) : "memory");
    __builtin_amdgcn_s_barrier();
    constexpr int pg = w + 2;
    if constexpr (pg < NW) {
      constexpr int o0 = ((pg % 3) * 8192);
      prefetch_slab(wp, SLAB, 2 * pg,     o0,        wave, lane);
      prefetch_slab(wp, SLAB, 2 * pg + 1, o0 + 4096, wave, lane);
    }
  }
  half8 bfr;
  if constexpr (FROM_ALPHA)
    bfr = *(const half8*)(ALPHA + ((wave * 6 + aks) * 64 + lane) * 8);
  else
    bfr = breg;
  constexpr int off = (w % 3) * 8192 + (GK & 1) * 4096;
  half8 wfv[8];
#pragma unroll
  for (int t = 0; t < 8; ++t)
    wfv[t] = *(const half8*)(SLAB + off + t * 512 + lane * 8);
  __builtin_amdgcn_s_setprio(1);
#pragma unroll
  for (int t = 0; t < 8; ++t)
    acc[t] = __builtin_amdgcn_mfma_f32_32x32x16_f16(wfv[t], bfr, acc[t], 0, 0, 0);
  __builtin_amdgcn_s_setprio(0);
}

__device__ __forceinline__ uint32_t pk2(float a, float b) {
  union { fp16x2 h; uint32_t u; } c;
  c.h = __builtin_amdgcn_cvt_pkrtz(a, b);
  return c.u;
}
__device__ __forceinline__ uint32_t shx32(uint32_t v) {
  return (uint32_t)__shfl_xor((int)v, 32, 64);
}
__device__ __forceinline__ half8 mk8(uint32_t a, uint32_t b, uint32_t c, uint32_t d) {
  union { uint32_t w[4]; half8 h; } u; u.w[0]=a; u.w[1]=b; u.w[2]=c; u.w[3]=d; return u.h;
}

// C fragment (row=(q&3)+8*(q>>2)+4*hi, col=ray) -> next-layer B fragments, in-register
__device__ __forceinline__ void epilogue(f32x16 (&acc)[8], half8 (&actB)[16], int hi) {
  const f32x16 ZV = {};
#pragma unroll
  for (int t = 0; t < 8; ++t) {
    float r[16];
#pragma unroll
    for (int q = 0; q < 16; ++q) r[q] = fmaxf(acc[t][q], 0.0f);
    const uint32_t A01 = pk2(r[0], r[1]),   A23 = pk2(r[2], r[3]);
    const uint32_t A45 = pk2(r[4], r[5]),   A67 = pk2(r[6], r[7]);
    const uint32_t A89 = pk2(r[8], r[9]),   Aab = pk2(r[10], r[11]);
    const uint32_t Acd = pk2(r[12], r[13]), Aef = pk2(r[14], r[15]);
    const uint32_t S01 = shx32(A01), S23 = shx32(A23), S45 = shx32(A45), S67 = shx32(A67);
    const uint32_t S89 = shx32(A89), Sab = shx32(Aab), Scd = shx32(Acd), Sef = shx32(Aef);
    actB[2 * t]     = mk8(hi ? S45 : A01, hi ? S67 : A23, hi ? A45 : S01, hi ? A67 : S23);
    actB[2 * t + 1] = mk8(hi ? Scd : A89, hi ? Sef : Aab, hi ? Acd : S89, hi ? Aef : Sab);
    acc[t] = ZV;
  }
}

__global__ __launch_bounds__(256, 2) void mlp_fw(
    const _Float16* __restrict__ apack, const float* __restrict__ cosin_buf,
    const _Float16* __restrict__ wp, const float* __restrict__ wl,
    const float* __restrict__ bl, float* __restrict__ out) {
  __shared__ _Float16 SLAB[3 * 8192];      // 48 KB: 3 group buffers x 2 slabs
  __shared__ _Float16 ALPHA[12288];        // 24 KB: 4 tiles x 6 ks x 64 x 8
  const int tid = threadIdx.x, wave = tid >> 6, lane = tid & 63;
  const int hi = lane >> 5, ray = lane & 31;
  const int rtile = blockIdx.x * 4 + wave;

  half8 bfrag = {};
  if (hi == 0) bfrag[0] = (_Float16)1.0f;

  // ---- prologue: stage ALPHA (6 gloads/thread), then groups 0 and 1 (8 gloads) ----
  const _Float16* abase = apack + (size_t)blockIdx.x * 12288;
#pragma unroll
  for (int s = 0; s < 6; ++s)
    gload16(abase + s * 2048 + wave * 512 + lane * 8, ALPHA + s * 2048 + wave * 512);
  prefetch_slab(wp, SLAB, 0, 0,           wave, lane);
  prefetch_slab(wp, SLAB, 1, 4096,        wave, lane);
  prefetch_slab(wp, SLAB, 2, 8192,        wave, lane);
  prefetch_slab(wp, SLAB, 3, 8192 + 4096, wave, lane);
  // window 0 preamble's vmcnt(4) drains ALPHA + group 0, leaves group 1 in flight.

  f32x16 acc[8]; const f32x16 ZV = {};
#pragma unroll
  for (int t = 0; t < 8; ++t) acc[t] = ZV;
  half8 actB[16];

#define KSA(GK, AKS) kstep<GK, true >(acc, bfrag, wp, SLAB, ALPHA, AKS, wave, lane)
#define KSR(GK, BFR) kstep<GK, false>(acc, (BFR), wp, SLAB, ALPHA, 0,   wave, lane)

  // L0: alpha(6) + bias
  static_for<0, 7>([&](auto ic) { constexpr int ks = decltype(ic)::val;
    if constexpr (ks < 6) KSA(0 + ks, ks); else KSR(0 + ks, bfrag); });
  epilogue(acc, actB, hi);
  // L1..L4
  static_for<0, 17>([&](auto ic) { constexpr int ks = decltype(ic)::val;
    if constexpr (ks < 16) KSR(7 + ks, actB[ks]); else KSR(7 + ks, bfrag); });
  epilogue(acc, actB, hi);
  static_for<0, 17>([&](auto ic) { constexpr int ks = decltype(ic)::val;
    if constexpr (ks < 16) KSR(24 + ks, actB[ks]); else KSR(24 + ks, bfrag); });
  epilogue(acc, actB, hi);
  static_for<0, 17>([&](auto ic) { constexpr int ks = decltype(ic)::val;
    if constexpr (ks < 16) KSR(41 + ks, actB[ks]); else KSR(41 + ks, bfrag); });
  epilogue(acc, actB, hi);
  static_for<0, 17>([&](auto ic) { constexpr int ks = decltype(ic)::val;
    if constexpr (ks < 16) KSR(58 + ks, actB[ks]); else KSR(58 + ks, bfrag); });
  epilogue(acc, actB, hi);
  // L5: alpha(6) + h(16) + bias
  static_for<0, 23>([&](auto ic) { constexpr int ks = decltype(ic)::val;
    if constexpr (ks < 6)       KSA(75 + ks, ks);
    else if constexpr (ks < 22) KSR(75 + ks, actB[ks - 6]);
    else                        KSR(75 + ks, bfrag); });
  epilogue(acc, actB, hi);
  // L6, L7
  static_for<0, 17>([&](auto ic) { constexpr int ks = decltype(ic)::val;
    if constexpr (ks < 16) KSR(98 + ks, actB[ks]); else KSR(98 + ks, bfrag); });
  epilogue(acc, actB, hi);
  static_for<0, 17>([&](auto ic) { constexpr int ks = decltype(ic)::val;
    if constexpr (ks < 16) KSR(115 + ks, actB[ks]); else KSR(115 + ks, bfrag); });
  epilogue(acc, actB, hi);
#undef KSA
#undef KSR

  // final: dot(h, w_last) -> sigmoid -> * cosin
  float p = 0.0f;
#pragma unroll
  for (int s = 0; s < 16; ++s) {
    const float* wq = wl + s * 16 + hi * 8;
#pragma unroll
    for (int j = 0; j < 8; ++j) p += (float)actB[s][j] * wq[j];
  }
  p += __shfl_xor(p, 32, 64);
  if (hi == 0) {
    const int rg = rtile * 32 + ray;
    out[rg] = (1.0f / (1.0f + __expf(-(p + bl[0])))) * cosin_buf[rg];
  }
}

// ================= launch =================
extern "C" void kernel_launch(void* const* d_in, const int* in_sizes, int n_in,
                              void* d_out, int out_size, void* d_ws, size_t ws_size,
                              hipStream_t stream) {
  const float* pts    = (const float*)d_in[0];
  const float* lights = (const float*)d_in[1];
  const float* sincol = (const float*)d_in[2];
  const float* normal = (const float*)d_in[3];
  const float* rb     = (const float*)d_in[4];
  const float* wf     = (const float*)d_in[5];
  const float* bf     = (const float*)d_in[6];
  const float* wlast  = (const float*)d_in[7];
  const float* blast  = (const float*)d_in[8];
  const float* w0 = (const float*)d_in[9];  const float* b0 = (const float*)d_in[10];
  const float* w1 = (const float*)d_in[11]; const float* b1 = (const float*)d_in[12];
  const float* w2 = (const float*)d_in[13]; const float* b2 = (const float*)d_in[14];
  const float* w3 = (const float*)d_in[15]; const float* b3 = (const float*)d_in[16];
  const float* w4 = (const float*)d_in[17]; const float* b4 = (const float*)d_in[18];
  const float* w5 = (const float*)d_in[19]; const float* b5 = (const float*)d_in[20];
  const float* w6 = (const float*)d_in[21]; const float* b6 = (const float*)d_in[22];
  const float* w7 = (const float*)d_in[23]; const float* b7 = (const float*)d_in[24];

  char* ws = (char*)d_ws;
  _Float16* apack  = (_Float16*)ws;                                  // NRAY*96 f16
  float* cosin_buf = (float*)(ws + (size_t)NRAY * 96 * 2);           // NRAY f32
  _Float16* wpack  = (_Float16*)(ws + (size_t)NRAY * 96 * 2 + (size_t)NRAY * 4);
  float* out = (float*)d_out;

  front<<<PA_BLOCKS + PREP_BLOCKS, 256, 0, stream>>>(
      pts, lights, sincol, normal, rb, wf, bf,
      w0, b0, w1, b1, w2, b2, w3, b3, w4, b4, w5, b5, w6, b6, w7, b7,
      wpack, apack, cosin_buf);
  mlp_fw<<<NRAY / 128, 256, 0, stream>>>(apack, cosin_buf, wpack, wlast, blast, out);
}

// Round 18
// 108.143 us; speedup vs baseline: 1.0765x; 1.0101x over previous
//
#include <hip/hip_runtime.h>
#include <math.h>
#include <stdint.h>

#define NPTS   512
#define NLIGHT 100
#define NRAY   (NPTS * NLIGHT)   // 51200
#define NS     50
#define NI     30
#define NF     80
#define HID    256
#define NEAR_  0.1f
#define FAR_   3.0f

typedef _Float16 half8  __attribute__((ext_vector_type(8)));
typedef __fp16   fp16x2 __attribute__((ext_vector_type(2)));
typedef float    f32x16 __attribute__((ext_vector_type(16)));

// ---------------- W stream layout (exact K, no padding) ----------------
// 130 ksteps, one 8KB slab each: wp[gk*4096 + t*512 + lane*8 + j]
//   n = t*32 + (lane&31);  k_local = ks*16 + (lane>>5)*8 + j   (A-fragment of 32x32x16)
// layer bases (ksteps): L0:0(6=5+bias) L1:6 L2:23 L3:40 L4:57 (17 ea)
//                       L5:74(22=5alpha+16h+bias) L6:96 L7:113 (17 ea) -> 130
// last kstep of each layer = bias tile; multiplied by e0 fragment.
// Windows of 2 ksteps; slab GROUPS triple-buffered in LDS (3 x 16KB). (R8-proven)
#define NKS  130
#define NW   (NKS / 2)           // 65 windows
#define WPACK_TOTAL (NKS * 4096)
#define PREP_BLOCKS (WPACK_TOTAL / 256)      // 2080 prep blocks (dispatched FIRST)
#define PA_BLOCKS   (NRAY / 8)               // 6400 phase_a blocks

__device__ __forceinline__ float sgpr_f(float v) {
  return __uint_as_float(__builtin_amdgcn_readfirstlane(__float_as_uint(v)));
}

// ================= sigma helper (wfr in SGPRs) =================
__device__ __forceinline__ float sigma_fast(float x, float y, float z,
                                            const float* __restrict__ wfr, float bf0) {
  float s = bf0 + wfr[0] * x + wfr[1] * y + wfr[2] * z;
  float sx = __sinf(x), cx = __cosf(x);
  float sy = __sinf(y), cy = __cosf(y);
  float sz = __sinf(z), cz = __cosf(z);
#pragma unroll
  for (int k = 0; k < 4; ++k) {
    s += wfr[3 + 6 * k + 0] * sx + wfr[3 + 6 * k + 1] * sy + wfr[3 + 6 * k + 2] * sz;
    s += wfr[3 + 6 * k + 3] * cx + wfr[3 + 6 * k + 4] * cy + wfr[3 + 6 * k + 5] * cz;
    if (k < 3) {
      const float sx2 = 2.0f * sx * cx, cx2 = 1.0f - 2.0f * sx * sx;
      const float sy2 = 2.0f * sy * cy, cy2 = 1.0f - 2.0f * sy * sy;
      const float sz2 = 2.0f * sz * cz, cz2 = 1.0f - 2.0f * sz * sz;
      sx = sx2; cx = cx2; sy = sy2; cy = cy2; sz = sz2; cz = cz2;
    }
  }
  return s;
}

// ================= merged front kernel: prep_w blocks FIRST, then phase_a =================
struct RayScratch2 {
  float cdf[NS - 1];   // 49 normalized cdf values (nondecreasing)
  float zs[NI];        // 30 importance samples (nondecreasing)
  float zall[NF];      // 80 merged z values
  float af[NF];        // 80 fine alphas for coalesced pack
};

__global__ __launch_bounds__(256, 8) void front(
    const float* __restrict__ pts, const float* __restrict__ lights,
    const float* __restrict__ sincol, const float* __restrict__ normal,
    const float* __restrict__ rb, const float* __restrict__ wf,
    const float* __restrict__ bf,
    const float* __restrict__ w0, const float* __restrict__ b0,
    const float* __restrict__ w1, const float* __restrict__ b1,
    const float* __restrict__ w2, const float* __restrict__ b2,
    const float* __restrict__ w3, const float* __restrict__ b3,
    const float* __restrict__ w4, const float* __restrict__ b4,
    const float* __restrict__ w5, const float* __restrict__ b5,
    const float* __restrict__ w6, const float* __restrict__ b6,
    const float* __restrict__ w7, const float* __restrict__ b7,
    _Float16* __restrict__ wp,
    _Float16* __restrict__ apack, float* __restrict__ cosin_out) {
  __shared__ RayScratch2 sh[8];

  if (blockIdx.x < PREP_BLOCKS) {
    // ---------------- prep_w part (first: gathers drain under phase_a's shadow) --------
    const int t = blockIdx.x * 256 + threadIdx.x;
    const int j    = t & 7;
    const int lane = (t >> 3) & 63;
    const int tile = (t >> 9) & 7;
    const int gk   = t >> 12;
    const int n    = tile * 32 + (lane & 31);
    const int kin  = (lane >> 5) * 8 + j;

    int base, KST; const float *W, *B;
    if      (gk < 6)   { base = 0;   KST = 6;  W = w0; B = b0; }
    else if (gk < 23)  { base = 6;   KST = 17; W = w1; B = b1; }
    else if (gk < 40)  { base = 23;  KST = 17; W = w2; B = b2; }
    else if (gk < 57)  { base = 40;  KST = 17; W = w3; B = b3; }
    else if (gk < 74)  { base = 57;  KST = 17; W = w4; B = b4; }
    else if (gk < 96)  { base = 74;  KST = 22; W = w5; B = b5; }
    else if (gk < 113) { base = 96;  KST = 17; W = w6; B = b6; }
    else               { base = 113; KST = 17; W = w7; B = b7; }
    const int ks = gk - base;
    const int k  = ks * 16 + kin;
    float v = 0.0f;
    if (ks == KST - 1) { if (kin == 0) v = B[n]; }
    else               { v = W[k * HID + n]; }   // exact-K: rows map directly (L5 incl.)
    wp[t] = (_Float16)v;
    return;
  }

  // ---------------- phase_a part: 2 rays per wave (half-wave = one ray) ----------------
  const int pablk = blockIdx.x - PREP_BLOCKS;
  const int wave = threadIdx.x >> 6;
  const int lane = threadIdx.x & 63;
  const int half = lane >> 5, l32 = lane & 31;
  const int ray  = (pablk * 4 + wave) * 2 + half;
  const int i = ray / NLIGHT, j = ray - i * NLIGHT;
  RayScratch2& S = sh[wave * 2 + half];

  float wfr[27];
#pragma unroll
  for (int k = 0; k < 27; ++k) wfr[k] = sgpr_f(wf[k]);
  const float bf0 = sgpr_f(bf[0]);
  const float DZ = (FAR_ - NEAR_) / (float)(NS - 1);

  const float px = pts[3 * i + 0], py = pts[3 * i + 1], pz = pts[3 * i + 2];
  const float dx = lights[3 * j + 0] - px;
  const float dy = lights[3 * j + 1] - py;
  const float dz = lights[3 * j + 2] - pz;
  const float nrm = sqrtf(dx * dx + dy * dy + dz * dz);
  const float rdx = dx / nrm, rdy = dy / nrm, rdz = dz / nrm;
  const float n2 = sqrtf(rdx * rdx + rdy * rdy + rdz * rdz);

  if (l32 == 0) {
    const float dotn = rdx * normal[3 * i + 0] + rdy * normal[3 * i + 1] + rdz * normal[3 * i + 2];
    cosin_out[ray] = (dotn > 0.0f) ? 1.0f : 0.0f;
  }

  const int k1 = l32, k2 = l32 + 32;
  const float sc = sincol[j];
  float a1, a2 = 0.0f;
  {
    const float z1 = NEAR_ + k1 * DZ;
    const float rb1 = rb[(size_t)ray * NS + k1];
    const float b1v = sc * z1 * 0.01f * (rb1 * 2.0f - 1.0f);
    const float s1v = sigma_fast(px + rdx * z1 + b1v, py + rdy * z1 + b1v, pz + rdz * z1 + b1v, wfr, bf0);
    a1 = 1.0f - __expf(-fmaxf(s1v, 0.0f) * DZ);
  }
  if (k2 < NS) {
    const float z2 = NEAR_ + k2 * DZ;
    const float rb2 = rb[(size_t)ray * NS + k2];
    const float b2v = sc * z2 * 0.01f * (rb2 * 2.0f - 1.0f);
    const float s2v = sigma_fast(px + rdx * z2 + b2v, py + rdy * z2 + b2v, pz + rdz * z2 + b2v, wfr, bf0);
    const float d2 = (k2 < NS - 1) ? DZ : 1e10f;
    a2 = 1.0f - __expf(-fmaxf(s2v, 0.0f) * d2);
  }

  // transmittance: exclusive product scan over 50 (two width-32 chunks)
  float v1 = 1.0f - a1 + 1e-10f;
  float v2 = (k2 < NS) ? (1.0f - a2 + 1e-10f) : 1.0f;
  float s1 = v1, s2 = v2;
#pragma unroll
  for (int off = 1; off < 32; off <<= 1) {
    const float o1 = __shfl_up(s1, off, 32);
    const float o2 = __shfl_up(s2, off, 32);
    if (l32 >= off) { s1 *= o1; s2 *= o2; }
  }
  const float tot1 = __shfl(s1, 31, 32);
  float e1 = __shfl_up(s1, 1, 32); if (l32 == 0) e1 = 1.0f;
  float e2 = __shfl_up(s2, 1, 32); e2 = (l32 == 0) ? tot1 : tot1 * e2;

  const float w1v = a1 * e1, w2v = a2 * e2;
  float ww1 = (k1 >= 1) ? (w1v + 1e-5f) : 0.0f;
  float ww2 = (k2 <= NS - 2 && k2 < NS) ? (w2v + 1e-5f) : 0.0f;

  float t = ww1 + ww2;
#pragma unroll
  for (int off = 1; off < 32; off <<= 1) t += __shfl_xor(t, off, 32);
  const float rn = 1.0f / t;

  float c1 = ww1, c2 = ww2;
#pragma unroll
  for (int off = 1; off < 32; off <<= 1) {
    const float o1 = __shfl_up(c1, off, 32);
    const float o2 = __shfl_up(c2, off, 32);
    if (l32 >= off) { c1 += o1; c2 += o2; }
  }
  const float tots1 = __shfl(c1, 31, 32);
  c2 += tots1;
  S.cdf[k1] = c1 * rn;
  if (k2 <= NS - 2) S.cdf[k2] = c2 * rn;

  // importance sampling: side='right' searchsorted via 6-step binary count
  float zsv = 0.0f;
  if (l32 < NI) {
    const float u = (float)l32 / (float)(NI - 1);
    int ind = 0;
#pragma unroll
    for (int step = 32; step >= 1; step >>= 1) {
      const int nxt = ind + step;
      if (nxt <= NS - 1 && S.cdf[nxt - 1] <= u) ind = nxt;
    }
    const int below = max(ind - 1, 0);
    const int above = min(ind, NS - 2);
    const float c0 = S.cdf[below], c1v = S.cdf[above];
    const float b0v = NEAR_ + ((float)below + 0.5f) * DZ;
    const float b1v = NEAR_ + ((float)above + 0.5f) * DZ;
    float den = c1v - c0;
    if (den < 1e-5f) den = 1.0f;
    zsv = b0v + (u - c0) / den * (b1v - b0v);
    S.zs[l32] = zsv;
  }

  // rank merge: count of zs[m] < z via 5-step binary lower-bound (zs nondecreasing)
  {
    const float z1 = NEAR_ + k1 * DZ;
    const float z2 = NEAR_ + k2 * DZ;
    int cnt1 = 0, cnt2 = 0;
#pragma unroll
    for (int step = 16; step >= 1; step >>= 1) {
      { const int nxt = cnt1 + step; if (nxt <= NI && S.zs[nxt - 1] < z1) cnt1 = nxt; }
      { const int nxt = cnt2 + step; if (nxt <= NI && S.zs[nxt - 1] < z2) cnt2 = nxt; }
    }
    S.zall[k1 + cnt1] = z1;
    if (k2 < NS) S.zall[k2 + cnt2] = z2;
  }
  if (l32 < NI) {
    int cnt = 0;
#pragma unroll
    for (int k = 0; k < NS; ++k)
      cnt += ((NEAR_ + k * DZ) <= zsv) ? 1 : 0;
    S.zall[l32 + cnt] = zsv;
  }

  // fine sigma into LDS af[80] (3 rounds of 32, guarded)
#pragma unroll
  for (int r = 0; r < 3; ++r) {
    const int k = l32 + 32 * r;
    if (k < NF) {
      const float z = S.zall[k];
      const float d = ((k < NF - 1) ? (S.zall[k + 1] - z) : 1e10f) * n2;
      const float sig = sigma_fast(px + rdx * z, py + rdy * z, pz + rdz * z, wfr, bf0);
      S.af[k] = 1.0f - __expf(-fmaxf(sig, 0.0f) * d);
    }
  }

  // coalesced pack: lanes 0..9 of each half-wave emit one half8 (16B) chunk each
  {
    const int rt = ray >> 5, rr = ray & 31;
    if (l32 < 10) {
      const int ks = l32 >> 1, hh = l32 & 1;
      half8 v;
#pragma unroll
      for (int jj = 0; jj < 8; ++jj) v[jj] = (_Float16)S.af[ks * 16 + hh * 8 + jj];
      *(half8*)(apack + ((size_t)(rt * 5 + ks) * 64 + rr + 32 * hh) * 8) = v;
    }
  }
}

// ======= Phase B (R8/R10-proven): windowed 2-kstep triple-buffered W-stream MLP =======
template <int V> struct IC { static constexpr int val = V; };
template <int I, int N, typename F>
__device__ __forceinline__ void static_for(F&& f) {
  if constexpr (I < N) { f(IC<I>{}); static_for<I + 1, N>((F&&)f); }
}

__device__ __forceinline__ void gload16(const _Float16* g, _Float16* l) {
  __builtin_amdgcn_global_load_lds(
      (const __attribute__((address_space(1))) uint32_t*)g,
      (__attribute__((address_space(3))) uint32_t*)l, 16, 0, 0);
}

// slab gk -> LDS f16 offset: group buffer ((gk>>1)%3)*8192 + (gk&1)*4096
__device__ __forceinline__ void prefetch_slab(const _Float16* __restrict__ wp,
                                              _Float16* SLAB, int gk, int off,
                                              int wave, int lane) {
  const _Float16* g = wp + ((size_t)gk << 12) + (wave << 9);
  _Float16* lb = SLAB + off + (wave << 9);
  gload16(g + lane * 8, lb);
  gload16(g + 2048 + lane * 8, lb + 2048);
}

// Window preamble (even GK): lgkm(0) -> counted vmcnt -> ONE barrier -> prefetch
// group GK/2+2 (2 slabs). Both ksteps of the window read staged slabs and MFMA.
template <int GK, bool FROM_ALPHA>
__device__ __forceinline__ void kstep(f32x16 (&acc)[8], const half8& breg,
                                      const _Float16* __restrict__ wp,
                                      _Float16* SLAB, const _Float16* ALPHA,
                                      int aks, int wave, int lane) {
  constexpr int w = GK >> 1;
  if constexpr ((GK & 1) == 0) {
    asm volatile("s_waitcnt lgkmcnt(0)" ::: "memory");
    constexpr int wait = (w < NW - 1) ? 4 : 0;
    asm volatile("s_waitcnt vmcnt(%0)" :: "i"(wait) : "memory");
    __builtin_amdgcn_s_barrier();
    constexpr int pg = w + 2;
    if constexpr (pg < NW) {
      constexpr int o0 = ((pg % 3) * 8192);
      prefetch_slab(wp, SLAB, 2 * pg,     o0,        wave, lane);
      prefetch_slab(wp, SLAB, 2 * pg + 1, o0 + 4096, wave, lane);
    }
  }
  half8 bfr;
  if constexpr (FROM_ALPHA)
    bfr = *(const half8*)(ALPHA + ((wave * 5 + aks) * 64 + lane) * 8);
  else
    bfr = breg;
  constexpr int off = (w % 3) * 8192 + (GK & 1) * 4096;
  half8 wfv[8];
#pragma unroll
  for (int t = 0; t < 8; ++t)
    wfv[t] = *(const half8*)(SLAB + off + t * 512 + lane * 8);
  __builtin_amdgcn_s_setprio(1);
#pragma unroll
  for (int t = 0; t < 8; ++t)
    acc[t] = __builtin_amdgcn_mfma_f32_32x32x16_f16(wfv[t], bfr, acc[t], 0, 0, 0);
  __builtin_amdgcn_s_setprio(0);
}

__device__ __forceinline__ uint32_t pk2(float a, float b) {
  union { fp16x2 h; uint32_t u; } c;
  c.h = __builtin_amdgcn_cvt_pkrtz(a, b);
  return c.u;
}
__device__ __forceinline__ uint32_t shx32(uint32_t v) {
  return (uint32_t)__shfl_xor((int)v, 32, 64);
}
__device__ __forceinline__ half8 mk8(uint32_t a, uint32_t b, uint32_t c, uint32_t d) {
  union { uint32_t w[4]; half8 h; } u; u.w[0]=a; u.w[1]=b; u.w[2]=c; u.w[3]=d; return u.h;
}

// C fragment (row=(q&3)+8*(q>>2)+4*hi, col=ray) -> next-layer B fragments, in-register
__device__ __forceinline__ void epilogue(f32x16 (&acc)[8], half8 (&actB)[16], int hi) {
  const f32x16 ZV = {};
#pragma unroll
  for (int t = 0; t < 8; ++t) {
    float r[16];
#pragma unroll
    for (int q = 0; q < 16; ++q) r[q] = fmaxf(acc[t][q], 0.0f);
    const uint32_t A01 = pk2(r[0], r[1]),   A23 = pk2(r[2], r[3]);
    const uint32_t A45 = pk2(r[4], r[5]),   A67 = pk2(r[6], r[7]);
    const uint32_t A89 = pk2(r[8], r[9]),   Aab = pk2(r[10], r[11]);
    const uint32_t Acd = pk2(r[12], r[13]), Aef = pk2(r[14], r[15]);
    const uint32_t S01 = shx32(A01), S23 = shx32(A23), S45 = shx32(A45), S67 = shx32(A67);
    const uint32_t S89 = shx32(A89), Sab = shx32(Aab), Scd = shx32(Acd), Sef = shx32(Aef);
    actB[2 * t]     = mk8(hi ? S45 : A01, hi ? S67 : A23, hi ? A45 : S01, hi ? A67 : S23);
    actB[2 * t + 1] = mk8(hi ? Scd : A89, hi ? Sef : Aab, hi ? Acd : S89, hi ? Aef : Sab);
    acc[t] = ZV;
  }
}

__global__ __launch_bounds__(256, 2) void mlp_fw(
    const _Float16* __restrict__ apack, const float* __restrict__ cosin_buf,
    const _Float16* __restrict__ wp, const float* __restrict__ wl,
    const float* __restrict__ bl, float* __restrict__ out) {
  __shared__ _Float16 SLAB[3 * 8192];      // 48 KB: 3 group buffers x 2 slabs
  __shared__ _Float16 ALPHA[10240];        // 20 KB: 4 tiles x 5 ks x 64 x 8
  const int tid = threadIdx.x, wave = tid >> 6, lane = tid & 63;
  const int hi = lane >> 5, ray = lane & 31;
  const int rtile = blockIdx.x * 4 + wave;

  half8 bfrag = {};
  if (hi == 0) bfrag[0] = (_Float16)1.0f;

  // ---- prologue: stage ALPHA (5 gloads/thread), then groups 0 and 1 (8 gloads) ----
  const _Float16* abase = apack + (size_t)blockIdx.x * 10240;
#pragma unroll
  for (int s = 0; s < 5; ++s)
    gload16(abase + s * 2048 + wave * 512 + lane * 8, ALPHA + s * 2048 + wave * 512);
  prefetch_slab(wp, SLAB, 0, 0,           wave, lane);
  prefetch_slab(wp, SLAB, 1, 4096,        wave, lane);
  prefetch_slab(wp, SLAB, 2, 8192,        wave, lane);
  prefetch_slab(wp, SLAB, 3, 8192 + 4096, wave, lane);
  // window 0 preamble's vmcnt(4) drains ALPHA + group 0, leaves group 1 in flight.

  f32x16 acc[8]; const f32x16 ZV = {};
#pragma unroll
  for (int t = 0; t < 8; ++t) acc[t] = ZV;
  half8 actB[16];

#define KSA(GK, AKS) kstep<GK, true >(acc, bfrag, wp, SLAB, ALPHA, AKS, wave, lane)
#define KSR(GK, BFR) kstep<GK, false>(acc, (BFR), wp, SLAB, ALPHA, 0,   wave, lane)

  // L0: alpha(5) + bias  (base 0)
  static_for<0, 6>([&](auto ic) { constexpr int ks = decltype(ic)::val;
    if constexpr (ks < 5) KSA(0 + ks, ks); else KSR(0 + ks, bfrag); });
  epilogue(acc, actB, hi);
  // L1..L4 (bases 6,23,40,57)
  static_for<0, 17>([&](auto ic) { constexpr int ks = decltype(ic)::val;
    if constexpr (ks < 16) KSR(6 + ks, actB[ks]); else KSR(6 + ks, bfrag); });
  epilogue(acc, actB, hi);
  static_for<0, 17>([&](auto ic) { constexpr int ks = decltype(ic)::val;
    if constexpr (ks < 16) KSR(23 + ks, actB[ks]); else KSR(23 + ks, bfrag); });
  epilogue(acc, actB, hi);
  static_for<0, 17>([&](auto ic) { constexpr int ks = decltype(ic)::val;
    if constexpr (ks < 16) KSR(40 + ks, actB[ks]); else KSR(40 + ks, bfrag); });
  epilogue(acc, actB, hi);
  static_for<0, 17>([&](auto ic) { constexpr int ks = decltype(ic)::val;
    if constexpr (ks < 16) KSR(57 + ks, actB[ks]); else KSR(57 + ks, bfrag); });
  epilogue(acc, actB, hi);
  // L5: alpha(5) + h(16) + bias (base 74)
  static_for<0, 22>([&](auto ic) { constexpr int ks = decltype(ic)::val;
    if constexpr (ks < 5)       KSA(74 + ks, ks);
    else if constexpr (ks < 21) KSR(74 + ks, actB[ks - 5]);
    else                        KSR(74 + ks, bfrag); });
  epilogue(acc, actB, hi);
  // L6, L7 (bases 96, 113)
  static_for<0, 17>([&](auto ic) { constexpr int ks = decltype(ic)::val;
    if constexpr (ks < 16) KSR(96 + ks, actB[ks]); else KSR(96 + ks, bfrag); });
  epilogue(acc, actB, hi);
  static_for<0, 17>([&](auto ic) { constexpr int ks = decltype(ic)::val;
    if constexpr (ks < 16) KSR(113 + ks, actB[ks]); else KSR(113 + ks, bfrag); });
  epilogue(acc, actB, hi);
#undef KSA
#undef KSR

  // final: dot(h, w_last) -> sigmoid -> * cosin
  float p = 0.0f;
#pragma unroll
  for (int s = 0; s < 16; ++s) {
    const float* wq = wl + s * 16 + hi * 8;
#pragma unroll
    for (int j = 0; j < 8; ++j) p += (float)actB[s][j] * wq[j];
  }
  p += __shfl_xor(p, 32, 64);
  if (hi == 0) {
    const int rg = rtile * 32 + ray;
    out[rg] = (1.0f / (1.0f + __expf(-(p + bl[0])))) * cosin_buf[rg];
  }
}

// ================= launch =================
extern "C" void kernel_launch(void* const* d_in, const int* in_sizes, int n_in,
                              void* d_out, int out_size, void* d_ws, size_t ws_size,
                              hipStream_t stream) {
  const float* pts    = (const float*)d_in[0];
  const float* lights = (const float*)d_in[1];
  const float* sincol = (const float*)d_in[2];
  const float* normal = (const float*)d_in[3];
  const float* rb     = (const float*)d_in[4];
  const float* wf     = (const float*)d_in[5];
  const float* bf     = (const float*)d_in[6];
  const float* wlast  = (const float*)d_in[7];
  const float* blast  = (const float*)d_in[8];
  const float* w0 = (const float*)d_in[9];  const float* b0 = (const float*)d_in[10];
  const float* w1 = (const float*)d_in[11]; const float* b1 = (const float*)d_in[12];
  const float* w2 = (const float*)d_in[13]; const float* b2 = (const float*)d_in[14];
  const float* w3 = (const float*)d_in[15]; const float* b3 = (const float*)d_in[16];
  const float* w4 = (const float*)d_in[17]; const float* b4 = (const float*)d_in[18];
  const float* w5 = (const float*)d_in[19]; const float* b5 = (const float*)d_in[20];
  const float* w6 = (const float*)d_in[21]; const float* b6 = (const float*)d_in[22];
  const float* w7 = (const float*)d_in[23]; const float* b7 = (const float*)d_in[24];

  char* ws = (char*)d_ws;
  _Float16* apack  = (_Float16*)ws;                                  // NRAY*80 f16
  float* cosin_buf = (float*)(ws + (size_t)NRAY * NF * 2);           // NRAY f32
  _Float16* wpack  = (_Float16*)(ws + (size_t)NRAY * NF * 2 + (size_t)NRAY * 4);
  float* out = (float*)d_out;

  front<<<PA_BLOCKS + PREP_BLOCKS, 256, 0, stream>>>(
      pts, lights, sincol, normal, rb, wf, bf,
      w0, b0, w1, b1, w2, b2, w3, b3, w4, b4, w5, b5, w6, b6, w7, b7,
      wpack, apack, cosin_buf);
  mlp_fw<<<NRAY / 128, 256, 0, stream>>>(apack, cosin_buf, wpack, wlast, blast, out);
}